// Round 1
// baseline (335.844 us; speedup 1.0000x reference)
//
#include <hip/hip_runtime.h>

#define PHI     1.618033988749895f
#define INV_PHI 0.6180339887498949f

__device__ __forceinline__ float phi_spiral(float v) {
    // sigmoid(v/phi) * (v*phi / (1+|v|))
    float e = __expf(-v * INV_PHI);               // v_exp_f32 path
    float s = __fdividef(1.0f, 1.0f + e);         // fast rcp, ~2 ulp
    float g = __fdividef(v * PHI, 1.0f + fabsf(v));
    return s * g;
}

__global__ __launch_bounds__(256) void seven_neurons_kernel(
    const float* __restrict__ x,
    const float* __restrict__ W_in,  const float* __restrict__ b_in,
    const float* __restrict__ Wn,    const float* __restrict__ bn,
    const float* __restrict__ W_int, const float* __restrict__ b_int,
    const float* __restrict__ gamma, const float* __restrict__ beta,
    const float* __restrict__ W_out, const float* __restrict__ b_out,
    float* __restrict__ out, int B)
{
    const int row = blockIdx.x * 256 + threadIdx.x;
    if (row >= B) return;
    const float* xr = x + (size_t)row * 256;

    // ---- stage 1: h = spiral(x @ W_in^T + b_in)   [256 -> 49]
    float h[49];
#pragma unroll
    for (int j = 0; j < 49; ++j) h[j] = b_in[j];   // uniform -> s_load

#pragma unroll 1
    for (int c = 0; c < 256; c += 16) {
        float xv[16];
#pragma unroll
        for (int u = 0; u < 4; ++u) {
            const float4 t = *reinterpret_cast<const float4*>(xr + c + u * 4);
            xv[u * 4 + 0] = t.x; xv[u * 4 + 1] = t.y;
            xv[u * 4 + 2] = t.z; xv[u * 4 + 3] = t.w;
        }
#pragma unroll
        for (int j = 0; j < 49; ++j) {
            const float* w = W_in + j * 256 + c;   // wave-uniform -> scalar loads
            float acc = h[j];
#pragma unroll
            for (int u = 0; u < 16; ++u) acc = fmaf(xv[u], w[u], acc);
            h[j] = acc;
        }
    }
#pragma unroll
    for (int j = 0; j < 49; ++j) h[j] = phi_spiral(h[j]);

    // ---- stage 2: combined = spiral(einsum('i,khi->kh'))   [49 -> 49]
    // z[m] = sum_i h[i] * Wn[m*49+i] + bn[m],  m = k*7+h  (matches reshape order)
    float comb[49];
#pragma unroll 1
    for (int m = 0; m < 49; ++m) {
        const float* w = Wn + m * 49;
        float acc = bn[m];
#pragma unroll
        for (int i = 0; i < 49; ++i) acc = fmaf(h[i], w[i], acc);
        comb[m] = phi_spiral(acc);
    }

    // ---- stage 3: integrated = spiral(comb @ W_int^T + b_int)   [49 -> 21]
    float integ[21];
#pragma unroll 1
    for (int o = 0; o < 21; ++o) {
        const float* w = W_int + o * 49;
        float acc = b_int[o];
#pragma unroll
        for (int i = 0; i < 49; ++i) acc = fmaf(comb[i], w[i], acc);
        integ[o] = phi_spiral(acc);
    }

    // ---- LayerNorm over 21 (eps = 1e-5)
    float mu = 0.f;
#pragma unroll
    for (int o = 0; o < 21; ++o) mu += integ[o];
    mu *= (1.0f / 21.0f);
    float var = 0.f;
#pragma unroll
    for (int o = 0; o < 21; ++o) { float d = integ[o] - mu; var = fmaf(d, d, var); }
    var *= (1.0f / 21.0f);
    const float r = rsqrtf(var + 1e-5f);
#pragma unroll
    for (int o = 0; o < 21; ++o)
        integ[o] = (integ[o] - mu) * r * gamma[o] + beta[o];

    // ---- out = normed @ W_out^T + b_out   [21 -> 4]
    float o4[4];
#pragma unroll
    for (int p = 0; p < 4; ++p) {
        const float* w = W_out + p * 21;
        float acc = b_out[p];
#pragma unroll
        for (int o = 0; o < 21; ++o) acc = fmaf(integ[o], w[o], acc);
        o4[p] = acc;
    }
    *reinterpret_cast<float4*>(out + (size_t)row * 4) =
        make_float4(o4[0], o4[1], o4[2], o4[3]);
}

extern "C" void kernel_launch(void* const* d_in, const int* in_sizes, int n_in,
                              void* d_out, int out_size, void* d_ws, size_t ws_size,
                              hipStream_t stream) {
    const float* x     = (const float*)d_in[0];
    const float* W_in  = (const float*)d_in[1];
    const float* b_in  = (const float*)d_in[2];
    const float* Wn    = (const float*)d_in[3];
    const float* bn    = (const float*)d_in[4];
    const float* W_int = (const float*)d_in[5];
    const float* b_int = (const float*)d_in[6];
    const float* gamma = (const float*)d_in[7];
    const float* beta  = (const float*)d_in[8];
    const float* W_out = (const float*)d_in[9];
    const float* b_out = (const float*)d_in[10];
    float* out = (float*)d_out;

    const int B = in_sizes[0] / 256;          // 262144
    const int grid = (B + 255) / 256;
    seven_neurons_kernel<<<grid, 256, 0, stream>>>(
        x, W_in, b_in, Wn, bn, W_int, b_int, gamma, beta, W_out, b_out, out, B);
}